// Round 1
// baseline (2999.153 us; speedup 1.0000x reference)
//
#include <hip/hip_runtime.h>

#define F 128

__global__ void init_deg_kernel(float* __restrict__ deg, int n) {
    int i = blockIdx.x * blockDim.x + threadIdx.x;
    if (i < n) deg[i] = 1.0f;  // self-loop weight
}

__global__ void edge_deg_kernel(const int* __restrict__ dst, const float* __restrict__ w,
                                float* __restrict__ deg, int e) {
    int i = blockIdx.x * blockDim.x + threadIdx.x;
    if (i < e) atomicAdd(&deg[dst[i]], w[i]);
}

__global__ void dinv_kernel(const float* __restrict__ deg, float* __restrict__ dinv, int n) {
    int i = blockIdx.x * blockDim.x + threadIdx.x;
    if (i < n) {
        float d = deg[i];
        dinv[i] = d > 0.f ? rsqrtf(d) : 0.f;
    }
}

// h = x @ W   (x: [n,128], W: [128,128] row-major)
// 128 threads per block (one per output col), 8 rows per block.
__global__ void gemm_kernel(const float* __restrict__ x, const float* __restrict__ W,
                            float* __restrict__ h, int n) {
    __shared__ float xs[8][F];
    int row0 = blockIdx.x * 8;
    int c = threadIdx.x;
    #pragma unroll
    for (int r = 0; r < 8; ++r) {
        int row = row0 + r;
        xs[r][c] = (row < n) ? x[(size_t)row * F + c] : 0.f;
    }
    __syncthreads();
    float acc[8] = {0.f, 0.f, 0.f, 0.f, 0.f, 0.f, 0.f, 0.f};
    for (int k = 0; k < F; ++k) {
        float wkc = W[k * F + c];        // coalesced across lanes; W is L1/L2-resident
        #pragma unroll
        for (int r = 0; r < 8; ++r) acc[r] += xs[r][k] * wkc;  // LDS broadcast read
    }
    #pragma unroll
    for (int r = 0; r < 8; ++r) {
        int row = row0 + r;
        if (row < n) h[(size_t)row * F + c] = acc[r];
    }
}

// One edge per 32 lanes; each lane handles 4 consecutive features (float4 gather).
__global__ void scatter_kernel(const int* __restrict__ src, const int* __restrict__ dst,
                               const float* __restrict__ w, const float* __restrict__ dinv,
                               const float* __restrict__ h, float* __restrict__ acc, int e) {
    int t = blockIdx.x * blockDim.x + threadIdx.x;
    int edge = t >> 5;
    int lane = t & 31;
    if (edge >= e) return;
    int s = src[edge];
    int d = dst[edge];
    float norm = dinv[s] * w[edge] * dinv[d];
    const float4* hs = (const float4*)(h + (size_t)s * F);
    float* ad = acc + (size_t)d * F;
    float4 v = hs[lane];
    atomicAdd(&ad[lane * 4 + 0], v.x * norm);
    atomicAdd(&ad[lane * 4 + 1], v.y * norm);
    atomicAdd(&ad[lane * 4 + 2], v.z * norm);
    atomicAdd(&ad[lane * 4 + 3], v.w * norm);
}

// val = acc[i,f] + h[i,f]*dinv[i]^2 + b[f];  out_emb = val; out_relu = relu(val)
__global__ void finalize_kernel(const float* __restrict__ h, const float* __restrict__ dinv,
                                const float* __restrict__ b,
                                float* __restrict__ out_emb, float* __restrict__ out_relu,
                                int n) {
    int idx = blockIdx.x * blockDim.x + threadIdx.x;
    if (idx >= n * F) return;
    int i = idx >> 7;
    int f = idx & (F - 1);
    float di = dinv[i];
    float val = out_emb[idx] + h[idx] * di * di + b[f];
    out_emb[idx] = val;
    out_relu[idx] = fmaxf(val, 0.f);
}

extern "C" void kernel_launch(void* const* d_in, const int* in_sizes, int n_in,
                              void* d_out, int out_size, void* d_ws, size_t ws_size,
                              hipStream_t stream) {
    const float* x  = (const float*)d_in[0];
    const float* W  = (const float*)d_in[1];
    const float* b  = (const float*)d_in[2];
    // d_in[3] = level (unused)
    const int*   ei = (const int*)d_in[4];
    const float* ew = (const float*)d_in[5];

    int n = in_sizes[0] / F;
    int e = in_sizes[4] / 2;
    const int* src = ei;
    const int* dst = ei + e;

    float* out_emb  = (float*)d_out;
    float* out_relu = out_emb + (size_t)n * F;

    float* h    = (float*)d_ws;                 // n*F floats
    float* deg  = h + (size_t)n * F;            // n floats
    float* dinv = deg + n;                      // n floats

    // zero the aggregation accumulator (d_out is poisoned before every launch)
    hipMemsetAsync(out_emb, 0, (size_t)n * F * sizeof(float), stream);

    init_deg_kernel<<<(n + 255) / 256, 256, 0, stream>>>(deg, n);
    edge_deg_kernel<<<(e + 255) / 256, 256, 0, stream>>>(dst, ew, deg, e);
    dinv_kernel<<<(n + 255) / 256, 256, 0, stream>>>(deg, dinv, n);
    gemm_kernel<<<(n + 7) / 8, 128, 0, stream>>>(x, W, h, n);

    long long scatter_threads = (long long)e * 32;
    int scatter_blocks = (int)((scatter_threads + 255) / 256);
    scatter_kernel<<<scatter_blocks, 256, 0, stream>>>(src, dst, ew, dinv, h, out_emb, e);

    finalize_kernel<<<(n * F + 255) / 256, 256, 0, stream>>>(h, dinv, b, out_emb, out_relu, n);
}

// Round 2
// 860.918 us; speedup vs baseline: 3.4837x; 3.4837x over previous
//
#include <hip/hip_runtime.h>

#define F 128

// deg starts at 1.0 (self-loop weight); cnt counts in-edges per dst.
__global__ void init_kernel(float* __restrict__ deg, int* __restrict__ cnt, int n) {
    int i = blockIdx.x * blockDim.x + threadIdx.x;
    if (i < n) { deg[i] = 1.0f; cnt[i] = 0; }
}

__global__ void hist_kernel(const int* __restrict__ dst, const float* __restrict__ w,
                            float* __restrict__ deg, int* __restrict__ cnt, int e) {
    int i = blockIdx.x * blockDim.x + threadIdx.x;
    if (i < e) {
        int d = dst[i];
        atomicAdd(&deg[d], w[i]);
        atomicAdd(&cnt[d], 1);
    }
}

__global__ void dinv_kernel(const float* __restrict__ deg, float* __restrict__ dinv, int n) {
    int i = blockIdx.x * blockDim.x + threadIdx.x;
    if (i < n) {
        float d = deg[i];
        dinv[i] = d > 0.f ? rsqrtf(d) : 0.f;
    }
}

// Single-block exclusive prefix sum of cnt[0..n) -> row_start[0..n], cursor copy.
__global__ void scan_kernel(const int* __restrict__ cnt, int* __restrict__ row_start,
                            int* __restrict__ cursor, int n) {
    __shared__ int partial[1024];
    int t = threadIdx.x;
    int chunk = (n + 1023) >> 10;
    int lo = t * chunk;
    int hi = min(lo + chunk, n);
    int s = 0;
    for (int i = lo; i < hi; ++i) s += cnt[i];
    partial[t] = s;
    __syncthreads();
    for (int off = 1; off < 1024; off <<= 1) {
        int v = (t >= off) ? partial[t - off] : 0;
        __syncthreads();
        partial[t] += v;
        __syncthreads();
    }
    int base = (t == 0) ? 0 : partial[t - 1];
    for (int i = lo; i < hi; ++i) {
        row_start[i] = base;
        cursor[i] = base;
        base += cnt[i];
    }
    if (t == 1023) row_start[n] = partial[1023];
}

// Scatter each edge into its dst's CSR slot; store precomputed norm.
__global__ void build_csr_kernel(const int* __restrict__ src, const int* __restrict__ dst,
                                 const float* __restrict__ w, const float* __restrict__ dinv,
                                 int* __restrict__ cursor,
                                 int* __restrict__ csr_src, float* __restrict__ csr_norm, int e) {
    int i = blockIdx.x * blockDim.x + threadIdx.x;
    if (i < e) {
        int s = src[i], d = dst[i];
        float norm = dinv[s] * w[i] * dinv[d];
        int pos = atomicAdd(&cursor[d], 1);
        csr_src[pos] = s;
        csr_norm[pos] = norm;
    }
}

// h = x @ W. Tile: 32 rows x 128 cols per block (256 threads), 4x4 register block.
__global__ __launch_bounds__(256) void gemm_kernel(const float* __restrict__ x,
                                                   const float* __restrict__ W,
                                                   float* __restrict__ h, int n) {
    __shared__ float xs[32][F];  // 16 KB
    int row0 = blockIdx.x * 32;
    int t = threadIdx.x;
    // cooperative load: 32 rows x 32 float4 each
    for (int v = t; v < 32 * 32; v += 256) {
        int r = v >> 5, c4 = v & 31;
        int row = row0 + r;
        float4 val = (row < n) ? ((const float4*)(x + (size_t)row * F))[c4]
                               : make_float4(0.f, 0.f, 0.f, 0.f);
        ((float4*)&xs[r][0])[c4] = val;
    }
    __syncthreads();

    int tx = t & 31;   // cols tx*4 .. tx*4+3
    int ty = t >> 5;   // rows ty*4 .. ty*4+3
    float acc[4][4] = {};
    const float4* Wv = (const float4*)W;  // W[k][c]: Wv[k*32 + c4]
    for (int k4 = 0; k4 < 32; ++k4) {
        float4 a[4];
        #pragma unroll
        for (int r = 0; r < 4; ++r)
            a[r] = ((const float4*)&xs[ty * 4 + r][0])[k4];  // ds_read_b128, 2-way bcast
        float4 w[4];
        #pragma unroll
        for (int kk = 0; kk < 4; ++kk)
            w[kk] = Wv[(k4 * 4 + kk) * 32 + tx];             // L1/L2-resident
        #pragma unroll
        for (int r = 0; r < 4; ++r) {
            #pragma unroll
            for (int kk = 0; kk < 4; ++kk) {
                float av = ((const float*)&a[r])[kk];
                acc[r][0] = fmaf(av, w[kk].x, acc[r][0]);
                acc[r][1] = fmaf(av, w[kk].y, acc[r][1]);
                acc[r][2] = fmaf(av, w[kk].z, acc[r][2]);
                acc[r][3] = fmaf(av, w[kk].w, acc[r][3]);
            }
        }
    }
    #pragma unroll
    for (int r = 0; r < 4; ++r) {
        int row = row0 + ty * 4 + r;
        if (row < n)
            ((float4*)(h + (size_t)row * F))[tx] =
                make_float4(acc[r][0], acc[r][1], acc[r][2], acc[r][3]);
    }
}

// One block per node, one thread per feature. No atomics. Fused bias+relu+both outputs.
__global__ __launch_bounds__(128) void aggregate_kernel(
        const float* __restrict__ h, const int* __restrict__ row_start,
        const int* __restrict__ csr_src, const float* __restrict__ csr_norm,
        const float* __restrict__ dinv, const float* __restrict__ b,
        float* __restrict__ out_emb, float* __restrict__ out_relu, int n) {
    int i = blockIdx.x;
    int f = threadIdx.x;
    int lo = row_start[i], hi = row_start[i + 1];
    float di = dinv[i];
    size_t base = (size_t)i * F + f;
    float acc = fmaf(h[base] * di, di, b[f]);       // self-loop: dinv_i * 1 * dinv_i
    for (int j = lo; j < hi; ++j) {
        int s = csr_src[j];        // uniform across block -> broadcast load
        float nw = csr_norm[j];
        acc = fmaf(h[(size_t)s * F + f], nw, acc);  // coalesced 512B row gather (L3)
    }
    out_emb[base] = acc;
    out_relu[base] = fmaxf(acc, 0.f);
}

extern "C" void kernel_launch(void* const* d_in, const int* in_sizes, int n_in,
                              void* d_out, int out_size, void* d_ws, size_t ws_size,
                              hipStream_t stream) {
    const float* x  = (const float*)d_in[0];
    const float* W  = (const float*)d_in[1];
    const float* b  = (const float*)d_in[2];
    const int*   ei = (const int*)d_in[4];
    const float* ew = (const float*)d_in[5];

    int n = in_sizes[0] / F;
    int e = in_sizes[4] / 2;
    const int* src = ei;
    const int* dst = ei + e;

    float* out_emb  = (float*)d_out;
    float* out_relu = out_emb + (size_t)n * F;

    // workspace layout (~66 MB)
    float* h         = (float*)d_ws;                    // n*F
    float* deg       = h + (size_t)n * F;               // n
    float* dinv      = deg + n;                         // n
    int*   cnt       = (int*)(dinv + n);                // n
    int*   row_start = cnt + n;                         // n+1
    int*   cursor    = row_start + n + 1;               // n
    int*   csr_src   = cursor + n;                      // e
    float* csr_norm  = (float*)(csr_src + e);           // e

    int nb_n = (n + 255) / 256;
    int nb_e = (e + 255) / 256;

    init_kernel<<<nb_n, 256, 0, stream>>>(deg, cnt, n);
    hist_kernel<<<nb_e, 256, 0, stream>>>(dst, ew, deg, cnt, e);
    dinv_kernel<<<nb_n, 256, 0, stream>>>(deg, dinv, n);
    scan_kernel<<<1, 1024, 0, stream>>>(cnt, row_start, cursor, n);
    build_csr_kernel<<<nb_e, 256, 0, stream>>>(src, dst, ew, dinv, cursor,
                                               csr_src, csr_norm, e);
    gemm_kernel<<<(n + 31) / 32, 256, 0, stream>>>(x, W, h, n);
    aggregate_kernel<<<n, 128, 0, stream>>>(h, row_start, csr_src, csr_norm,
                                            dinv, b, out_emb, out_relu, n);
}

// Round 3
// 587.497 us; speedup vs baseline: 5.1050x; 1.4654x over previous
//
#include <hip/hip_runtime.h>

#define F 128
#define SCAN_CHUNK 1024   // elements per block in the multi-block scan

// deg starts at 1.0 (self-loop weight); cnt counts in-edges per dst.
__global__ void init_kernel(float* __restrict__ deg, int* __restrict__ cnt, int n) {
    int i = blockIdx.x * blockDim.x + threadIdx.x;
    if (i < n) { deg[i] = 1.0f; cnt[i] = 0; }
}

__global__ void hist_kernel(const int* __restrict__ dst, const float* __restrict__ w,
                            float* __restrict__ deg, int* __restrict__ cnt, int e) {
    int i = blockIdx.x * blockDim.x + threadIdx.x;
    if (i < e) {
        int d = dst[i];
        atomicAdd(&deg[d], w[i]);
        atomicAdd(&cnt[d], 1);
    }
}

__global__ void dinv_kernel(const float* __restrict__ deg, float* __restrict__ dinv, int n) {
    int i = blockIdx.x * blockDim.x + threadIdx.x;
    if (i < n) {
        float d = deg[i];
        dinv[i] = d > 0.f ? rsqrtf(d) : 0.f;
    }
}

// ---- multi-block exclusive scan of cnt -> row_start/cursor ----
// Pass 1: per-block (1024-element chunk) total.
__global__ __launch_bounds__(256) void scan_partial_kernel(const int* __restrict__ cnt,
                                                           int* __restrict__ partials, int n) {
    __shared__ int red[256];
    int t = threadIdx.x;
    int lo = blockIdx.x * SCAN_CHUNK + t * 4;
    int s = 0;
    #pragma unroll
    for (int k = 0; k < 4; ++k) {
        int i = lo + k;
        if (i < n) s += cnt[i];
    }
    red[t] = s;
    __syncthreads();
    for (int off = 128; off > 0; off >>= 1) {
        if (t < off) red[t] += red[t + off];
        __syncthreads();
    }
    if (t == 0) partials[blockIdx.x] = red[0];
}

// Pass 2: exclusive-scan the partials in place (single small block; nb <= 1024).
__global__ __launch_bounds__(1024) void scan_partials_kernel(int* __restrict__ partials, int nb) {
    __shared__ int sh[1024];
    int t = threadIdx.x;
    int v = (t < nb) ? partials[t] : 0;
    sh[t] = v;
    __syncthreads();
    for (int off = 1; off < 1024; off <<= 1) {
        int u = (t >= off) ? sh[t - off] : 0;
        __syncthreads();
        sh[t] += u;
        __syncthreads();
    }
    if (t < nb) partials[t] = sh[t] - v;   // exclusive
}

// Pass 3: per-chunk local exclusive scan + global offset -> row_start, cursor.
__global__ __launch_bounds__(256) void scan_final_kernel(const int* __restrict__ cnt,
                                                         const int* __restrict__ partials,
                                                         int* __restrict__ row_start,
                                                         int* __restrict__ cursor, int n) {
    __shared__ int red[256];
    int t = threadIdx.x;
    int blk = blockIdx.x;
    int lo = blk * SCAN_CHUNK + t * 4;
    int v[4];
    int s = 0;
    #pragma unroll
    for (int k = 0; k < 4; ++k) {
        int i = lo + k;
        v[k] = (i < n) ? cnt[i] : 0;
        s += v[k];
    }
    red[t] = s;
    __syncthreads();
    for (int off = 1; off < 256; off <<= 1) {
        int u = (t >= off) ? red[t - off] : 0;
        __syncthreads();
        red[t] += u;
        __syncthreads();
    }
    int base = partials[blk] + ((t == 0) ? 0 : red[t - 1]);
    #pragma unroll
    for (int k = 0; k < 4; ++k) {
        int i = lo + k;
        if (i < n) { row_start[i] = base; cursor[i] = base; base += v[k]; }
    }
    if (blk == gridDim.x - 1 && t == 255) row_start[n] = partials[blk] + red[255];
}

// Scatter each edge into its dst's CSR slot; store precomputed norm.
__global__ void build_csr_kernel(const int* __restrict__ src, const int* __restrict__ dst,
                                 const float* __restrict__ w, const float* __restrict__ dinv,
                                 int* __restrict__ cursor,
                                 int* __restrict__ csr_src, float* __restrict__ csr_norm, int e) {
    int i = blockIdx.x * blockDim.x + threadIdx.x;
    if (i < e) {
        int s = src[i], d = dst[i];
        float norm = dinv[s] * w[i] * dinv[d];
        int pos = atomicAdd(&cursor[d], 1);
        csr_src[pos] = s;
        csr_norm[pos] = norm;
    }
}

// h = x @ W. Tile: 32 rows x 128 cols per block (256 threads), 4x4 register block.
__global__ __launch_bounds__(256) void gemm_kernel(const float* __restrict__ x,
                                                   const float* __restrict__ W,
                                                   float* __restrict__ h, int n) {
    __shared__ float xs[32][F];  // 16 KB
    int row0 = blockIdx.x * 32;
    int t = threadIdx.x;
    for (int v = t; v < 32 * 32; v += 256) {
        int r = v >> 5, c4 = v & 31;
        int row = row0 + r;
        float4 val = (row < n) ? ((const float4*)(x + (size_t)row * F))[c4]
                               : make_float4(0.f, 0.f, 0.f, 0.f);
        ((float4*)&xs[r][0])[c4] = val;
    }
    __syncthreads();

    int tx = t & 31;   // cols tx*4 .. tx*4+3
    int ty = t >> 5;   // rows ty*4 .. ty*4+3
    float acc[4][4] = {};
    const float4* Wv = (const float4*)W;
    for (int k4 = 0; k4 < 32; ++k4) {
        float4 a[4];
        #pragma unroll
        for (int r = 0; r < 4; ++r)
            a[r] = ((const float4*)&xs[ty * 4 + r][0])[k4];
        float4 w[4];
        #pragma unroll
        for (int kk = 0; kk < 4; ++kk)
            w[kk] = Wv[(k4 * 4 + kk) * 32 + tx];
        #pragma unroll
        for (int r = 0; r < 4; ++r) {
            #pragma unroll
            for (int kk = 0; kk < 4; ++kk) {
                float av = ((const float*)&a[r])[kk];
                acc[r][0] = fmaf(av, w[kk].x, acc[r][0]);
                acc[r][1] = fmaf(av, w[kk].y, acc[r][1]);
                acc[r][2] = fmaf(av, w[kk].z, acc[r][2]);
                acc[r][3] = fmaf(av, w[kk].w, acc[r][3]);
            }
        }
    }
    #pragma unroll
    for (int r = 0; r < 4; ++r) {
        int row = row0 + ty * 4 + r;
        if (row < n)
            ((float4*)(h + (size_t)row * F))[tx] =
                make_float4(acc[r][0], acc[r][1], acc[r][2], acc[r][3]);
    }
}

// One block per node, one thread per feature. Edge (src,norm) staged in LDS.
__global__ __launch_bounds__(128) void aggregate_kernel(
        const float* __restrict__ h, const int* __restrict__ row_start,
        const int* __restrict__ csr_src, const float* __restrict__ csr_norm,
        const float* __restrict__ dinv, const float* __restrict__ b,
        float* __restrict__ out_emb, float* __restrict__ out_relu, int n) {
    __shared__ int   ls[128];
    __shared__ float ln[128];
    int i = blockIdx.x;
    int f = threadIdx.x;
    int lo = row_start[i], hi = row_start[i + 1];
    float di = dinv[i];
    size_t base = (size_t)i * F + f;
    float acc = fmaf(h[base] * di, di, b[f]);       // self-loop term
    for (int c = lo; c < hi; c += 128) {
        int m = min(128, hi - c);
        if (f < m) { ls[f] = csr_src[c + f]; ln[f] = csr_norm[c + f]; }  // coalesced
        __syncthreads();
        for (int j = 0; j < m; ++j)
            acc = fmaf(h[(size_t)ls[j] * F + f], ln[j], acc);  // 512B row gather (L3)
        __syncthreads();
    }
    out_emb[base] = acc;
    out_relu[base] = fmaxf(acc, 0.f);
}

extern "C" void kernel_launch(void* const* d_in, const int* in_sizes, int n_in,
                              void* d_out, int out_size, void* d_ws, size_t ws_size,
                              hipStream_t stream) {
    const float* x  = (const float*)d_in[0];
    const float* W  = (const float*)d_in[1];
    const float* b  = (const float*)d_in[2];
    const int*   ei = (const int*)d_in[4];
    const float* ew = (const float*)d_in[5];

    int n = in_sizes[0] / F;
    int e = in_sizes[4] / 2;
    const int* src = ei;
    const int* dst = ei + e;

    float* out_emb  = (float*)d_out;
    float* out_relu = out_emb + (size_t)n * F;

    // workspace layout (~66 MB)
    float* h         = (float*)d_ws;                    // n*F
    float* deg       = h + (size_t)n * F;               // n
    float* dinv      = deg + n;                         // n
    int*   cnt       = (int*)(dinv + n);                // n
    int*   row_start = cnt + n;                         // n+1
    int*   cursor    = row_start + n + 1;               // n
    int*   partials  = cursor + n;                      // up to 1024
    int*   csr_src   = partials + 1024;                 // e
    float* csr_norm  = (float*)(csr_src + e);           // e

    int nb_n = (n + 255) / 256;
    int nb_e = (e + 255) / 256;
    int nb_scan = (n + SCAN_CHUNK - 1) / SCAN_CHUNK;    // 98 for n=100k

    init_kernel<<<nb_n, 256, 0, stream>>>(deg, cnt, n);
    hist_kernel<<<nb_e, 256, 0, stream>>>(dst, ew, deg, cnt, e);
    dinv_kernel<<<nb_n, 256, 0, stream>>>(deg, dinv, n);
    scan_partial_kernel<<<nb_scan, 256, 0, stream>>>(cnt, partials, n);
    scan_partials_kernel<<<1, 1024, 0, stream>>>(partials, nb_scan);
    scan_final_kernel<<<nb_scan, 256, 0, stream>>>(cnt, partials, row_start, cursor, n);
    build_csr_kernel<<<nb_e, 256, 0, stream>>>(src, dst, ew, dinv, cursor,
                                               csr_src, csr_norm, e);
    gemm_kernel<<<(n + 31) / 32, 256, 0, stream>>>(x, W, h, n);
    aggregate_kernel<<<n, 128, 0, stream>>>(h, row_start, csr_src, csr_norm,
                                            dinv, b, out_emb, out_relu, n);
}

// Round 4
// 491.884 us; speedup vs baseline: 6.0973x; 1.1944x over previous
//
#include <hip/hip_runtime.h>

#define F 128
#define K_REP 8   // histogram/cursor replication factor (contention reduction)

// Pass 1: replicated packed histogram. hi24 = in-edge count, lo40 = sum(w) in 2^-24 fixed pt.
__global__ __launch_bounds__(256) void hist_kernel(const int* __restrict__ dst,
                                                   const float* __restrict__ w,
                                                   unsigned long long* __restrict__ packed,
                                                   int n, int e) {
    int i = blockIdx.x * 256 + threadIdx.x;
    if (i >= e) return;
    int d = dst[i];
    unsigned long long v = (1ULL << 40) |
                           (unsigned long long)(unsigned)(w[i] * 16777216.0f);
    int k = blockIdx.x & (K_REP - 1);
    atomicAdd(&packed[(size_t)k * n + d], v);
}

// Scan stage 1: per-block (256 nodes x K_REP replicas) edge-count total.
__global__ __launch_bounds__(256) void scan1_kernel(const unsigned long long* __restrict__ packed,
                                                    int* __restrict__ partials, int n) {
    __shared__ int red[256];
    int t = threadIdx.x;
    int d = blockIdx.x * 256 + t;
    int s = 0;
    if (d < n) {
        #pragma unroll
        for (int k = 0; k < K_REP; ++k)
            s += (int)(packed[(size_t)k * n + d] >> 40);
    }
    red[t] = s;
    __syncthreads();
    for (int off = 128; off > 0; off >>= 1) {
        if (t < off) red[t] += red[t + off];
        __syncthreads();
    }
    if (t == 0) partials[blockIdx.x] = red[0];
}

// Scan stage 2: exclusive scan of block partials (nb <= 1024).
__global__ __launch_bounds__(1024) void scan2_kernel(int* __restrict__ partials, int nb) {
    __shared__ int sh[1024];
    int t = threadIdx.x;
    int v = (t < nb) ? partials[t] : 0;
    sh[t] = v;
    __syncthreads();
    for (int off = 1; off < 1024; off <<= 1) {
        int u = (t >= off) ? sh[t - off] : 0;
        __syncthreads();
        sh[t] += u;
        __syncthreads();
    }
    if (t < nb) partials[t] = sh[t] - v;   // exclusive
}

// Scan stage 3: per-node offsets -> row_start + per-replica cursors; fused dinv.
__global__ __launch_bounds__(256) void scan3_kernel(const unsigned long long* __restrict__ packed,
                                                    const int* __restrict__ partials,
                                                    int* __restrict__ cursor_rep,
                                                    int* __restrict__ row_start,
                                                    float* __restrict__ dinv, int n) {
    __shared__ int red[256];
    int t = threadIdx.x;
    int d = blockIdx.x * 256 + t;
    int cnt_k[K_REP];
    float wsum = 0.f;
    int tot = 0;
    if (d < n) {
        #pragma unroll
        for (int k = 0; k < K_REP; ++k) {
            unsigned long long p = packed[(size_t)k * n + d];
            cnt_k[k] = (int)(p >> 40);
            wsum += (float)(p & 0xFFFFFFFFFFULL);
            tot += cnt_k[k];
        }
    }
    red[t] = tot;
    __syncthreads();
    for (int off = 1; off < 256; off <<= 1) {   // inclusive scan
        int u = (t >= off) ? red[t - off] : 0;
        __syncthreads();
        red[t] += u;
        __syncthreads();
    }
    if (d < n) {
        int base = partials[blockIdx.x] + red[t] - tot;   // exclusive
        row_start[d] = base;
        int run = base;
        #pragma unroll
        for (int k = 0; k < K_REP; ++k) {
            cursor_rep[(size_t)k * n + d] = run;
            run += cnt_k[k];
        }
        if (d == n - 1) row_start[n] = run;
        dinv[d] = rsqrtf(1.0f + wsum * (1.0f / 16777216.0f));   // self-loop weight 1
    }
}

// Scatter each edge into its (replica,dst) CSR slot; store (src, norm) as one 8B entry.
__global__ __launch_bounds__(256) void build_csr_kernel(const int* __restrict__ src,
                                                        const int* __restrict__ dst,
                                                        const float* __restrict__ w,
                                                        const float* __restrict__ dinv,
                                                        int* __restrict__ cursor_rep,
                                                        int2* __restrict__ csr,
                                                        int n, int e) {
    int i = blockIdx.x * 256 + threadIdx.x;   // MUST match hist's edge->replica mapping
    if (i >= e) return;
    int s = src[i], d = dst[i];
    float norm = dinv[s] * w[i] * dinv[d];
    int k = blockIdx.x & (K_REP - 1);
    int pos = atomicAdd(&cursor_rep[(size_t)k * n + d], 1);
    csr[pos] = make_int2(s, __float_as_int(norm));
}

// h = x @ W. Tile: 32 rows x 128 cols per block (256 threads), 4x4 register block.
__global__ __launch_bounds__(256) void gemm_kernel(const float* __restrict__ x,
                                                   const float* __restrict__ W,
                                                   float* __restrict__ h, int n) {
    __shared__ float xs[32][F];  // 16 KB
    int row0 = blockIdx.x * 32;
    int t = threadIdx.x;
    for (int v = t; v < 32 * 32; v += 256) {
        int r = v >> 5, c4 = v & 31;
        int row = row0 + r;
        float4 val = (row < n) ? ((const float4*)(x + (size_t)row * F))[c4]
                               : make_float4(0.f, 0.f, 0.f, 0.f);
        ((float4*)&xs[r][0])[c4] = val;
    }
    __syncthreads();

    int tx = t & 31;
    int ty = t >> 5;
    float acc[4][4] = {};
    const float4* Wv = (const float4*)W;
    for (int k4 = 0; k4 < 32; ++k4) {
        float4 a[4];
        #pragma unroll
        for (int r = 0; r < 4; ++r)
            a[r] = ((const float4*)&xs[ty * 4 + r][0])[k4];
        float4 w[4];
        #pragma unroll
        for (int kk = 0; kk < 4; ++kk)
            w[kk] = Wv[(k4 * 4 + kk) * 32 + tx];
        #pragma unroll
        for (int r = 0; r < 4; ++r) {
            #pragma unroll
            for (int kk = 0; kk < 4; ++kk) {
                float av = ((const float*)&a[r])[kk];
                acc[r][0] = fmaf(av, w[kk].x, acc[r][0]);
                acc[r][1] = fmaf(av, w[kk].y, acc[r][1]);
                acc[r][2] = fmaf(av, w[kk].z, acc[r][2]);
                acc[r][3] = fmaf(av, w[kk].w, acc[r][3]);
            }
        }
    }
    #pragma unroll
    for (int r = 0; r < 4; ++r) {
        int row = row0 + ty * 4 + r;
        if (row < n)
            ((float4*)(h + (size_t)row * F))[tx] =
                make_float4(acc[r][0], acc[r][1], acc[r][2], acc[r][3]);
    }
}

// One wave per node, 2 features per lane (float2). readlane -> scalar edge broadcast.
__global__ __launch_bounds__(256) void aggregate_kernel(
        const float* __restrict__ h, const int* __restrict__ row_start,
        const int2* __restrict__ csr, const float* __restrict__ dinv,
        const float* __restrict__ b,
        float* __restrict__ out_emb, float* __restrict__ out_relu, int n) {
    int wave = threadIdx.x >> 6;
    int lane = threadIdx.x & 63;
    int i = blockIdx.x * 4 + wave;
    if (i >= n) return;
    int lo = row_start[i], hi = row_start[i + 1];
    float di = dinv[i];
    const float2* h2 = (const float2*)h;
    float2 hv = h2[(size_t)i * 64 + lane];
    float2 bv = ((const float2*)b)[lane];
    float2 acc;
    acc.x = fmaf(hv.x * di, di, bv.x);   // self-loop: dinv_i^2 * h_i + b
    acc.y = fmaf(hv.y * di, di, bv.y);
    for (int c = lo; c < hi; c += 64) {
        int m = min(64, hi - c);
        int sv = 0, nvi = 0;
        if (lane < m) { int2 en = csr[c + lane]; sv = en.x; nvi = en.y; }
        for (int j = 0; j < m; ++j) {
            int s = __builtin_amdgcn_readlane(sv, j);                       // SGPR
            float nw = __int_as_float(__builtin_amdgcn_readlane(nvi, j));   // SGPR
            float2 g = h2[(size_t)s * 64 + lane];   // scalar base + lane*8, coalesced 512B
            acc.x = fmaf(g.x, nw, acc.x);
            acc.y = fmaf(g.y, nw, acc.y);
        }
    }
    ((float2*)out_emb)[(size_t)i * 64 + lane] = acc;
    ((float2*)out_relu)[(size_t)i * 64 + lane] =
        make_float2(fmaxf(acc.x, 0.f), fmaxf(acc.y, 0.f));
}

extern "C" void kernel_launch(void* const* d_in, const int* in_sizes, int n_in,
                              void* d_out, int out_size, void* d_ws, size_t ws_size,
                              hipStream_t stream) {
    const float* x  = (const float*)d_in[0];
    const float* W  = (const float*)d_in[1];
    const float* b  = (const float*)d_in[2];
    const int*   ei = (const int*)d_in[4];
    const float* ew = (const float*)d_in[5];

    int n = in_sizes[0] / F;
    int e = in_sizes[4] / 2;
    const int* src = ei;
    const int* dst = ei + e;

    float* out_emb  = (float*)d_out;
    float* out_relu = out_emb + (size_t)n * F;

    // workspace layout (~68 MB). packed (6.4MB) aliases csr (12.8MB): packed is
    // dead after scan3; csr is written only in build_csr which runs after.
    size_t nF = (size_t)n * F;
    float* h = (float*)d_ws;                                     // n*F f32
    int2* csr = (int2*)(h + nF);                                 // e entries
    unsigned long long* packed = (unsigned long long*)csr;       // K_REP*n u64 (alias)
    size_t shared_elems = (size_t)e > (size_t)K_REP * n ? (size_t)e : (size_t)K_REP * n;
    int*   cursor_rep = (int*)(csr + shared_elems);              // K_REP*n
    int*   row_start  = cursor_rep + (size_t)K_REP * n;          // n+1
    float* dinv       = (float*)(row_start + n + 1);             // n
    int*   partials   = (int*)(dinv + n);                        // <=1024

    int nb_e    = (e + 255) / 256;
    int nb_scan = (n + 255) / 256;   // 391 for n=100k (scan2 handles <=1024)

    hipMemsetAsync(packed, 0, (size_t)K_REP * n * sizeof(unsigned long long), stream);
    hist_kernel<<<nb_e, 256, 0, stream>>>(dst, ew, packed, n, e);
    scan1_kernel<<<nb_scan, 256, 0, stream>>>(packed, partials, n);
    scan2_kernel<<<1, 1024, 0, stream>>>(partials, nb_scan);
    scan3_kernel<<<nb_scan, 256, 0, stream>>>(packed, partials, cursor_rep,
                                              row_start, dinv, n);
    gemm_kernel<<<(n + 31) / 32, 256, 0, stream>>>(x, W, h, n);
    build_csr_kernel<<<nb_e, 256, 0, stream>>>(src, dst, ew, dinv, cursor_rep,
                                               csr, n, e);
    aggregate_kernel<<<(n + 3) / 4, 256, 0, stream>>>(h, row_start, csr, dinv, b,
                                                      out_emb, out_relu, n);
}

// Round 5
// 439.977 us; speedup vs baseline: 6.8166x; 1.1180x over previous
//
#include <hip/hip_runtime.h>

#define F 128
#define K_REP 16  // histogram/cursor replication factor (contention reduction)

typedef unsigned int uint;
typedef unsigned short ushort;

// round-to-nearest-even f32 -> bf16 (values are finite; no NaN handling needed)
static __device__ inline ushort f2bf(float f) {
    uint u = __float_as_uint(f);
    return (ushort)((u + 0x7FFF + ((u >> 16) & 1)) >> 16);
}

// Pass 1: replicated packed histogram. hi24 = in-edge count, lo40 = sum(w) in 2^-24 fixed pt.
__global__ __launch_bounds__(256) void hist_kernel(const int* __restrict__ dst,
                                                   const float* __restrict__ w,
                                                   unsigned long long* __restrict__ packed,
                                                   int n, int e) {
    int i = blockIdx.x * 256 + threadIdx.x;
    if (i >= e) return;
    int d = dst[i];
    unsigned long long v = (1ULL << 40) |
                           (unsigned long long)(unsigned)(w[i] * 16777216.0f);
    int k = blockIdx.x & (K_REP - 1);
    atomicAdd(&packed[(size_t)k * n + d], v);
}

// Scan stage 1: per-block (256 nodes x K_REP replicas) edge-count total.
__global__ __launch_bounds__(256) void scan1_kernel(const unsigned long long* __restrict__ packed,
                                                    int* __restrict__ partials, int n) {
    __shared__ int red[256];
    int t = threadIdx.x;
    int d = blockIdx.x * 256 + t;
    int s = 0;
    if (d < n) {
        #pragma unroll
        for (int k = 0; k < K_REP; ++k)
            s += (int)(packed[(size_t)k * n + d] >> 40);
    }
    red[t] = s;
    __syncthreads();
    for (int off = 128; off > 0; off >>= 1) {
        if (t < off) red[t] += red[t + off];
        __syncthreads();
    }
    if (t == 0) partials[blockIdx.x] = red[0];
}

// Scan stage 2: exclusive scan of block partials (nb <= 1024).
__global__ __launch_bounds__(1024) void scan2_kernel(int* __restrict__ partials, int nb) {
    __shared__ int sh[1024];
    int t = threadIdx.x;
    int v = (t < nb) ? partials[t] : 0;
    sh[t] = v;
    __syncthreads();
    for (int off = 1; off < 1024; off <<= 1) {
        int u = (t >= off) ? sh[t - off] : 0;
        __syncthreads();
        sh[t] += u;
        __syncthreads();
    }
    if (t < nb) partials[t] = sh[t] - v;   // exclusive
}

// Scan stage 3: per-node offsets -> row_start + per-replica cursors; fused dinv.
__global__ __launch_bounds__(256) void scan3_kernel(const unsigned long long* __restrict__ packed,
                                                    const int* __restrict__ partials,
                                                    int* __restrict__ cursor_rep,
                                                    int* __restrict__ row_start,
                                                    float* __restrict__ dinv, int n) {
    __shared__ int red[256];
    int t = threadIdx.x;
    int d = blockIdx.x * 256 + t;
    int cnt_k[K_REP];
    float wsum = 0.f;
    int tot = 0;
    if (d < n) {
        #pragma unroll
        for (int k = 0; k < K_REP; ++k) {
            unsigned long long p = packed[(size_t)k * n + d];
            cnt_k[k] = (int)(p >> 40);
            wsum += (float)(p & 0xFFFFFFFFFFULL);
            tot += cnt_k[k];
        }
    }
    red[t] = tot;
    __syncthreads();
    for (int off = 1; off < 256; off <<= 1) {   // inclusive scan
        int u = (t >= off) ? red[t - off] : 0;
        __syncthreads();
        red[t] += u;
        __syncthreads();
    }
    if (d < n) {
        int base = partials[blockIdx.x] + red[t] - tot;   // exclusive
        row_start[d] = base;
        int run = base;
        #pragma unroll
        for (int k = 0; k < K_REP; ++k) {
            cursor_rep[(size_t)k * n + d] = run;
            run += cnt_k[k];
        }
        if (d == n - 1) row_start[n] = run;
        dinv[d] = rsqrtf(1.0f + wsum * (1.0f / 16777216.0f));   // self-loop weight 1
    }
}

// Scatter each edge into its (replica,dst) CSR slot; store (src, norm) as one 8B entry.
__global__ __launch_bounds__(256) void build_csr_kernel(const int* __restrict__ src,
                                                        const int* __restrict__ dst,
                                                        const float* __restrict__ w,
                                                        const float* __restrict__ dinv,
                                                        int* __restrict__ cursor_rep,
                                                        int2* __restrict__ csr,
                                                        int n, int e) {
    int i = blockIdx.x * 256 + threadIdx.x;   // MUST match hist's edge->replica mapping
    if (i >= e) return;
    int s = src[i], d = dst[i];
    float norm = dinv[s] * w[i] * dinv[d];
    int k = blockIdx.x & (K_REP - 1);
    int pos = atomicAdd(&cursor_rep[(size_t)k * n + d], 1);
    csr[pos] = make_int2(s, __float_as_int(norm));
}

// h = x @ W, output bf16. Tile: 32 rows x 128 cols per block, 4x4 register block.
__global__ __launch_bounds__(256) void gemm_kernel(const float* __restrict__ x,
                                                   const float* __restrict__ W,
                                                   ushort* __restrict__ hb, int n) {
    __shared__ float xs[32][F];  // 16 KB
    int row0 = blockIdx.x * 32;
    int t = threadIdx.x;
    for (int v = t; v < 32 * 32; v += 256) {
        int r = v >> 5, c4 = v & 31;
        int row = row0 + r;
        float4 val = (row < n) ? ((const float4*)(x + (size_t)row * F))[c4]
                               : make_float4(0.f, 0.f, 0.f, 0.f);
        ((float4*)&xs[r][0])[c4] = val;
    }
    __syncthreads();

    int tx = t & 31;   // cols tx*4 .. tx*4+3
    int ty = t >> 5;   // rows ty*4 .. ty*4+3
    float acc[4][4] = {};
    const float4* Wv = (const float4*)W;
    for (int k4 = 0; k4 < 32; ++k4) {
        float4 a[4];
        #pragma unroll
        for (int r = 0; r < 4; ++r)
            a[r] = ((const float4*)&xs[ty * 4 + r][0])[k4];
        float4 w[4];
        #pragma unroll
        for (int kk = 0; kk < 4; ++kk)
            w[kk] = Wv[(k4 * 4 + kk) * 32 + tx];
        #pragma unroll
        for (int r = 0; r < 4; ++r) {
            #pragma unroll
            for (int kk = 0; kk < 4; ++kk) {
                float av = ((const float*)&a[r])[kk];
                acc[r][0] = fmaf(av, w[kk].x, acc[r][0]);
                acc[r][1] = fmaf(av, w[kk].y, acc[r][1]);
                acc[r][2] = fmaf(av, w[kk].z, acc[r][2]);
                acc[r][3] = fmaf(av, w[kk].w, acc[r][3]);
            }
        }
    }
    #pragma unroll
    for (int r = 0; r < 4; ++r) {
        int row = row0 + ty * 4 + r;
        if (row < n) {
            ushort4 o = make_ushort4(f2bf(acc[r][0]), f2bf(acc[r][1]),
                                     f2bf(acc[r][2]), f2bf(acc[r][3]));
            *(ushort4*)(hb + (size_t)row * F + tx * 4) = o;   // 8B aligned, coalesced 256B
        }
    }
}

// One wave per node, 2 bf16 features per lane (one dword). readlane edge broadcast,
// 8-deep explicit gather batch for memory-level parallelism.
__global__ __launch_bounds__(256) void aggregate_kernel(
        const ushort* __restrict__ hb, const int* __restrict__ row_start,
        const int2* __restrict__ csr, const float* __restrict__ dinv,
        const float* __restrict__ b,
        float* __restrict__ out_emb, float* __restrict__ out_relu, int n) {
    int wave = threadIdx.x >> 6;
    int lane = threadIdx.x & 63;
    int i = blockIdx.x * 4 + wave;
    if (i >= n) return;
    int lo = row_start[i], hi = row_start[i + 1];
    float di = dinv[i];
    const uint* h32 = (const uint*)hb;   // one dword = features {2*lane, 2*lane+1}
    uint hvu = h32[(size_t)i * 64 + lane];
    float2 bv = ((const float2*)b)[lane];
    float2 acc;
    acc.x = fmaf(__uint_as_float(hvu << 16) * di, di, bv.x);          // self-loop
    acc.y = fmaf(__uint_as_float(hvu & 0xFFFF0000u) * di, di, bv.y);
    for (int c = lo; c < hi; c += 64) {
        int m = min(64, hi - c);
        int sv = 0, nvi = 0;   // lanes >= m keep (src=0, norm=0) -> harmless padding
        if (lane < m) { int2 en = csr[c + lane]; sv = en.x; nvi = en.y; }
        int mp = (m + 7) & ~7;
        for (int j = 0; j < mp; j += 8) {
            int ss[8]; float nw[8]; uint g[8];
            #pragma unroll
            for (int u = 0; u < 8; ++u) {
                ss[u] = __builtin_amdgcn_readlane(sv, j + u);
                nw[u] = __uint_as_float((uint)__builtin_amdgcn_readlane(nvi, j + u));
            }
            #pragma unroll
            for (int u = 0; u < 8; ++u)
                g[u] = h32[(size_t)ss[u] * 64 + lane];   // 8 independent 256B row gathers
            #pragma unroll
            for (int u = 0; u < 8; ++u) {
                acc.x = fmaf(__uint_as_float(g[u] << 16), nw[u], acc.x);
                acc.y = fmaf(__uint_as_float(g[u] & 0xFFFF0000u), nw[u], acc.y);
            }
        }
    }
    ((float2*)out_emb)[(size_t)i * 64 + lane] = acc;
    ((float2*)out_relu)[(size_t)i * 64 + lane] =
        make_float2(fmaxf(acc.x, 0.f), fmaxf(acc.y, 0.f));
}

extern "C" void kernel_launch(void* const* d_in, const int* in_sizes, int n_in,
                              void* d_out, int out_size, void* d_ws, size_t ws_size,
                              hipStream_t stream) {
    const float* x  = (const float*)d_in[0];
    const float* W  = (const float*)d_in[1];
    const float* b  = (const float*)d_in[2];
    const int*   ei = (const int*)d_in[4];
    const float* ew = (const float*)d_in[5];

    int n = in_sizes[0] / F;
    int e = in_sizes[4] / 2;
    const int* src = ei;
    const int* dst = ei + e;

    float* out_emb  = (float*)d_out;
    float* out_relu = out_emb + (size_t)n * F;

    // workspace layout (~58 MB). packed (K_REP*n u64) aliases csr (e int2):
    // packed is dead after scan3; csr is written only in build_csr (after scan3).
    ushort* hb = (ushort*)d_ws;                                  // n*F bf16 (25.6 MB)
    int2* csr = (int2*)(hb + (size_t)n * F);
    unsigned long long* packed = (unsigned long long*)csr;
    size_t shared_elems = (size_t)e > (size_t)K_REP * n ? (size_t)e : (size_t)K_REP * n;
    int*   cursor_rep = (int*)(csr + shared_elems);              // K_REP*n
    int*   row_start  = cursor_rep + (size_t)K_REP * n;          // n+1
    float* dinv       = (float*)(row_start + n + 1);             // n
    int*   partials   = (int*)(dinv + n);                        // <=1024

    int nb_e    = (e + 255) / 256;
    int nb_scan = (n + 255) / 256;   // 391 for n=100k (scan2 handles <=1024)

    hipMemsetAsync(packed, 0, (size_t)K_REP * n * sizeof(unsigned long long), stream);
    hist_kernel<<<nb_e, 256, 0, stream>>>(dst, ew, packed, n, e);
    scan1_kernel<<<nb_scan, 256, 0, stream>>>(packed, partials, n);
    scan2_kernel<<<1, 1024, 0, stream>>>(partials, nb_scan);
    scan3_kernel<<<nb_scan, 256, 0, stream>>>(packed, partials, cursor_rep,
                                              row_start, dinv, n);
    gemm_kernel<<<(n + 31) / 32, 256, 0, stream>>>(x, W, hb, n);
    build_csr_kernel<<<nb_e, 256, 0, stream>>>(src, dst, ew, dinv, cursor_rep,
                                               csr, n, e);
    aggregate_kernel<<<(n + 3) / 4, 256, 0, stream>>>(hb, row_start, csr, dinv, b,
                                                      out_emb, out_relu, n);
}

// Round 6
// 407.054 us; speedup vs baseline: 7.3679x; 1.0809x over previous
//
#include <hip/hip_runtime.h>

#define F 128
#define K_REP 16  // histogram/segment replication factor (contention reduction)

typedef unsigned int uint;
typedef unsigned short ushort;

// round-to-nearest-even f32 -> bf16 (values are finite; no NaN handling needed)
static __device__ inline ushort f2bf(float f) {
    uint u = __float_as_uint(f);
    return (ushort)((u + 0x7FFF + ((u >> 16) & 1)) >> 16);
}

// Pass 1: replicated packed histogram. hi24 = in-edge count, lo40 = sum(w) in 2^-24
// fixed pt. The RETURNED old count is this edge's rank within its (k,d) segment —
// stored coalesced so build_csr needs no atomic at all.
__global__ __launch_bounds__(256) void hist_kernel(const int* __restrict__ dst,
                                                   const float* __restrict__ w,
                                                   unsigned long long* __restrict__ packed,
                                                   int* __restrict__ rank,
                                                   int n, int e) {
    int i = blockIdx.x * 256 + threadIdx.x;
    if (i >= e) return;
    int d = dst[i];
    unsigned long long v = (1ULL << 40) |
                           (unsigned long long)(unsigned)(w[i] * 16777216.0f);
    int k = blockIdx.x & (K_REP - 1);
    unsigned long long old = atomicAdd(&packed[(size_t)k * n + d], v);
    rank[i] = (int)(old >> 40);
}

// Scan stage 1: per-block (256 nodes x K_REP replicas) edge-count total.
__global__ __launch_bounds__(256) void scan1_kernel(const unsigned long long* __restrict__ packed,
                                                    int* __restrict__ partials, int n) {
    __shared__ int red[256];
    int t = threadIdx.x;
    int d = blockIdx.x * 256 + t;
    int s = 0;
    if (d < n) {
        #pragma unroll
        for (int k = 0; k < K_REP; ++k)
            s += (int)(packed[(size_t)k * n + d] >> 40);
    }
    red[t] = s;
    __syncthreads();
    for (int off = 128; off > 0; off >>= 1) {
        if (t < off) red[t] += red[t + off];
        __syncthreads();
    }
    if (t == 0) partials[blockIdx.x] = red[0];
}

// Scan stage 2: exclusive scan of block partials (nb <= 1024).
__global__ __launch_bounds__(1024) void scan2_kernel(int* __restrict__ partials, int nb) {
    __shared__ int sh[1024];
    int t = threadIdx.x;
    int v = (t < nb) ? partials[t] : 0;
    sh[t] = v;
    __syncthreads();
    for (int off = 1; off < 1024; off <<= 1) {
        int u = (t >= off) ? sh[t - off] : 0;
        __syncthreads();
        sh[t] += u;
        __syncthreads();
    }
    if (t < nb) partials[t] = sh[t] - v;   // exclusive
}

// Scan stage 3: per-node offsets -> row_start + per-replica segment starts; fused dinv.
__global__ __launch_bounds__(256) void scan3_kernel(const unsigned long long* __restrict__ packed,
                                                    const int* __restrict__ partials,
                                                    int* __restrict__ seg_start,
                                                    int* __restrict__ row_start,
                                                    float* __restrict__ dinv, int n) {
    __shared__ int red[256];
    int t = threadIdx.x;
    int d = blockIdx.x * 256 + t;
    int cnt_k[K_REP];
    float wsum = 0.f;
    int tot = 0;
    if (d < n) {
        #pragma unroll
        for (int k = 0; k < K_REP; ++k) {
            unsigned long long p = packed[(size_t)k * n + d];
            cnt_k[k] = (int)(p >> 40);
            wsum += (float)(p & 0xFFFFFFFFFFULL);
            tot += cnt_k[k];
        }
    }
    red[t] = tot;
    __syncthreads();
    for (int off = 1; off < 256; off <<= 1) {   // inclusive scan
        int u = (t >= off) ? red[t - off] : 0;
        __syncthreads();
        red[t] += u;
        __syncthreads();
    }
    if (d < n) {
        int base = partials[blockIdx.x] + red[t] - tot;   // exclusive
        row_start[d] = base;
        int run = base;
        #pragma unroll
        for (int k = 0; k < K_REP; ++k) {
            seg_start[(size_t)k * n + d] = run;
            run += cnt_k[k];
        }
        if (d == n - 1) row_start[n] = run;
        dinv[d] = rsqrtf(1.0f + wsum * (1.0f / 16777216.0f));   // self-loop weight 1
    }
}

// Scatter each edge into its precomputed (replica,dst,rank) CSR slot. ZERO atomics:
// slot = seg_start[k][d] + rank[i]. All loads independent; store is fire-and-forget.
__global__ __launch_bounds__(256) void build_csr_kernel(const int* __restrict__ src,
                                                        const int* __restrict__ dst,
                                                        const float* __restrict__ w,
                                                        const float* __restrict__ dinv,
                                                        const int* __restrict__ seg_start,
                                                        const int* __restrict__ rank,
                                                        int2* __restrict__ csr,
                                                        int n, int e) {
    int i = blockIdx.x * 256 + threadIdx.x;   // MUST match hist's edge->replica mapping
    if (i >= e) return;
    int s = src[i], d = dst[i];
    float norm = dinv[s] * w[i] * dinv[d];
    int k = blockIdx.x & (K_REP - 1);
    int pos = seg_start[(size_t)k * n + d] + rank[i];
    csr[pos] = make_int2(s, __float_as_int(norm));
}

// h = x @ W, output bf16. Tile: 32 rows x 128 cols per block, 4x4 register block.
__global__ __launch_bounds__(256) void gemm_kernel(const float* __restrict__ x,
                                                   const float* __restrict__ W,
                                                   ushort* __restrict__ hb, int n) {
    __shared__ float xs[32][F];  // 16 KB
    int row0 = blockIdx.x * 32;
    int t = threadIdx.x;
    for (int v = t; v < 32 * 32; v += 256) {
        int r = v >> 5, c4 = v & 31;
        int row = row0 + r;
        float4 val = (row < n) ? ((const float4*)(x + (size_t)row * F))[c4]
                               : make_float4(0.f, 0.f, 0.f, 0.f);
        ((float4*)&xs[r][0])[c4] = val;
    }
    __syncthreads();

    int tx = t & 31;   // cols tx*4 .. tx*4+3
    int ty = t >> 5;   // rows ty*4 .. ty*4+3
    float acc[4][4] = {};
    const float4* Wv = (const float4*)W;
    for (int k4 = 0; k4 < 32; ++k4) {
        float4 a[4];
        #pragma unroll
        for (int r = 0; r < 4; ++r)
            a[r] = ((const float4*)&xs[ty * 4 + r][0])[k4];
        float4 w[4];
        #pragma unroll
        for (int kk = 0; kk < 4; ++kk)
            w[kk] = Wv[(k4 * 4 + kk) * 32 + tx];
        #pragma unroll
        for (int r = 0; r < 4; ++r) {
            #pragma unroll
            for (int kk = 0; kk < 4; ++kk) {
                float av = ((const float*)&a[r])[kk];
                acc[r][0] = fmaf(av, w[kk].x, acc[r][0]);
                acc[r][1] = fmaf(av, w[kk].y, acc[r][1]);
                acc[r][2] = fmaf(av, w[kk].z, acc[r][2]);
                acc[r][3] = fmaf(av, w[kk].w, acc[r][3]);
            }
        }
    }
    #pragma unroll
    for (int r = 0; r < 4; ++r) {
        int row = row0 + ty * 4 + r;
        if (row < n) {
            ushort4 o = make_ushort4(f2bf(acc[r][0]), f2bf(acc[r][1]),
                                     f2bf(acc[r][2]), f2bf(acc[r][3]));
            *(ushort4*)(hb + (size_t)row * F + tx * 4) = o;   // 8B aligned, coalesced 256B
        }
    }
}

// One wave per node, 2 bf16 features per lane (one dword). readlane edge broadcast,
// 8-deep explicit gather batch for memory-level parallelism.
__global__ __launch_bounds__(256) void aggregate_kernel(
        const ushort* __restrict__ hb, const int* __restrict__ row_start,
        const int2* __restrict__ csr, const float* __restrict__ dinv,
        const float* __restrict__ b,
        float* __restrict__ out_emb, float* __restrict__ out_relu, int n) {
    int wave = threadIdx.x >> 6;
    int lane = threadIdx.x & 63;
    int i = blockIdx.x * 4 + wave;
    if (i >= n) return;
    int lo = row_start[i], hi = row_start[i + 1];
    float di = dinv[i];
    const uint* h32 = (const uint*)hb;   // one dword = features {2*lane, 2*lane+1}
    uint hvu = h32[(size_t)i * 64 + lane];
    float2 bv = ((const float2*)b)[lane];
    float2 acc;
    acc.x = fmaf(__uint_as_float(hvu << 16) * di, di, bv.x);          // self-loop
    acc.y = fmaf(__uint_as_float(hvu & 0xFFFF0000u) * di, di, bv.y);
    for (int c = lo; c < hi; c += 64) {
        int m = min(64, hi - c);
        int sv = 0, nvi = 0;   // lanes >= m keep (src=0, norm=0) -> harmless padding
        if (lane < m) { int2 en = csr[c + lane]; sv = en.x; nvi = en.y; }
        int mp = (m + 7) & ~7;
        for (int j = 0; j < mp; j += 8) {
            int ss[8]; float nw[8]; uint g[8];
            #pragma unroll
            for (int u = 0; u < 8; ++u) {
                ss[u] = __builtin_amdgcn_readlane(sv, j + u);
                nw[u] = __uint_as_float((uint)__builtin_amdgcn_readlane(nvi, j + u));
            }
            #pragma unroll
            for (int u = 0; u < 8; ++u)
                g[u] = h32[(size_t)ss[u] * 64 + lane];   // 8 independent 256B row gathers
            #pragma unroll
            for (int u = 0; u < 8; ++u) {
                acc.x = fmaf(__uint_as_float(g[u] << 16), nw[u], acc.x);
                acc.y = fmaf(__uint_as_float(g[u] & 0xFFFF0000u), nw[u], acc.y);
            }
        }
    }
    ((float2*)out_emb)[(size_t)i * 64 + lane] = acc;
    ((float2*)out_relu)[(size_t)i * 64 + lane] =
        make_float2(fmaxf(acc.x, 0.f), fmaxf(acc.y, 0.f));
}

extern "C" void kernel_launch(void* const* d_in, const int* in_sizes, int n_in,
                              void* d_out, int out_size, void* d_ws, size_t ws_size,
                              hipStream_t stream) {
    const float* x  = (const float*)d_in[0];
    const float* W  = (const float*)d_in[1];
    const float* b  = (const float*)d_in[2];
    const int*   ei = (const int*)d_in[4];
    const float* ew = (const float*)d_in[5];

    int n = in_sizes[0] / F;
    int e = in_sizes[4] / 2;
    const int* src = ei;
    const int* dst = ei + e;

    float* out_emb  = (float*)d_out;
    float* out_relu = out_emb + (size_t)n * F;

    // workspace layout (~52 MB). packed (K_REP*n u64) aliases csr (e int2):
    // packed is dead after scan3; csr is written only in build_csr (after scan3).
    ushort* hb = (ushort*)d_ws;                                  // n*F bf16 (25.6 MB)
    int2* csr = (int2*)(hb + (size_t)n * F);
    unsigned long long* packed = (unsigned long long*)csr;
    size_t shared_elems = (size_t)e > (size_t)K_REP * n ? (size_t)e : (size_t)K_REP * n;
    int*   seg_start  = (int*)(csr + shared_elems);              // K_REP*n
    int*   row_start  = seg_start + (size_t)K_REP * n;           // n+1
    float* dinv       = (float*)(row_start + n + 1);             // n
    int*   partials   = (int*)(dinv + n);                        // <=1024
    int*   rank       = partials + 1024;                         // e

    int nb_e    = (e + 255) / 256;
    int nb_scan = (n + 255) / 256;   // 391 for n=100k (scan2 handles <=1024)

    hipMemsetAsync(packed, 0, (size_t)K_REP * n * sizeof(unsigned long long), stream);
    hist_kernel<<<nb_e, 256, 0, stream>>>(dst, ew, packed, rank, n, e);
    scan1_kernel<<<nb_scan, 256, 0, stream>>>(packed, partials, n);
    scan2_kernel<<<1, 1024, 0, stream>>>(partials, nb_scan);
    scan3_kernel<<<nb_scan, 256, 0, stream>>>(packed, partials, seg_start,
                                              row_start, dinv, n);
    gemm_kernel<<<(n + 31) / 32, 256, 0, stream>>>(x, W, hb, n);
    build_csr_kernel<<<nb_e, 256, 0, stream>>>(src, dst, ew, dinv, seg_start, rank,
                                               csr, n, e);
    aggregate_kernel<<<(n + 3) / 4, 256, 0, stream>>>(hb, row_start, csr, dinv, b,
                                                      out_emb, out_relu, n);
}

// Round 7
// 373.882 us; speedup vs baseline: 8.0216x; 1.0887x over previous
//
#include <hip/hip_runtime.h>

#define F 128
#define K_REP 16  // histogram/segment replication factor (contention reduction)

typedef unsigned int uint;
typedef unsigned short ushort;

typedef __attribute__((ext_vector_type(8))) short bf16x8;
typedef __attribute__((ext_vector_type(4))) float f32x4;

union U4B8 { uint4 u; bf16x8 v; };

// round-to-nearest-even f32 -> bf16 (values are finite; no NaN handling needed)
static __device__ inline ushort f2bf(float f) {
    uint u = __float_as_uint(f);
    return (ushort)((u + 0x7FFF + ((u >> 16) & 1)) >> 16);
}
static __device__ inline float bf2f(ushort h) {
    return __uint_as_float((uint)h << 16);
}

// Pass 1: replicated packed histogram. hi24 = in-edge count, lo40 = sum(w) in 2^-24
// fixed pt. The RETURNED old count is this edge's rank within its (k,d) segment.
__global__ __launch_bounds__(256) void hist_kernel(const int* __restrict__ dst,
                                                   const float* __restrict__ w,
                                                   unsigned long long* __restrict__ packed,
                                                   int* __restrict__ rank,
                                                   int n, int e) {
    int i = blockIdx.x * 256 + threadIdx.x;
    if (i >= e) return;
    int d = dst[i];
    unsigned long long v = (1ULL << 40) |
                           (unsigned long long)(unsigned)(w[i] * 16777216.0f);
    int k = blockIdx.x & (K_REP - 1);
    unsigned long long old = atomicAdd(&packed[(size_t)k * n + d], v);
    rank[i] = (int)(old >> 40);
}

// Scan stage 1: per-block (256 nodes x K_REP replicas) edge-count total.
__global__ __launch_bounds__(256) void scan1_kernel(const unsigned long long* __restrict__ packed,
                                                    int* __restrict__ partials, int n) {
    __shared__ int red[256];
    int t = threadIdx.x;
    int d = blockIdx.x * 256 + t;
    int s = 0;
    if (d < n) {
        #pragma unroll
        for (int k = 0; k < K_REP; ++k)
            s += (int)(packed[(size_t)k * n + d] >> 40);
    }
    red[t] = s;
    __syncthreads();
    for (int off = 128; off > 0; off >>= 1) {
        if (t < off) red[t] += red[t + off];
        __syncthreads();
    }
    if (t == 0) partials[blockIdx.x] = red[0];
}

// Scan stage 2: exclusive scan of block partials (nb <= 1024).
__global__ __launch_bounds__(1024) void scan2_kernel(int* __restrict__ partials, int nb) {
    __shared__ int sh[1024];
    int t = threadIdx.x;
    int v = (t < nb) ? partials[t] : 0;
    sh[t] = v;
    __syncthreads();
    for (int off = 1; off < 1024; off <<= 1) {
        int u = (t >= off) ? sh[t - off] : 0;
        __syncthreads();
        sh[t] += u;
        __syncthreads();
    }
    if (t < nb) partials[t] = sh[t] - v;   // exclusive
}

// Scan stage 3: per-node offsets -> row_start + per-replica segment starts; fused dinv.
__global__ __launch_bounds__(256) void scan3_kernel(const unsigned long long* __restrict__ packed,
                                                    const int* __restrict__ partials,
                                                    int* __restrict__ seg_start,
                                                    int* __restrict__ row_start,
                                                    float* __restrict__ dinv, int n) {
    __shared__ int red[256];
    int t = threadIdx.x;
    int d = blockIdx.x * 256 + t;
    int cnt_k[K_REP];
    float wsum = 0.f;
    int tot = 0;
    if (d < n) {
        #pragma unroll
        for (int k = 0; k < K_REP; ++k) {
            unsigned long long p = packed[(size_t)k * n + d];
            cnt_k[k] = (int)(p >> 40);
            wsum += (float)(p & 0xFFFFFFFFFFULL);
            tot += cnt_k[k];
        }
    }
    red[t] = tot;
    __syncthreads();
    for (int off = 1; off < 256; off <<= 1) {   // inclusive scan
        int u = (t >= off) ? red[t - off] : 0;
        __syncthreads();
        red[t] += u;
        __syncthreads();
    }
    if (d < n) {
        int base = partials[blockIdx.x] + red[t] - tot;   // exclusive
        row_start[d] = base;
        int run = base;
        #pragma unroll
        for (int k = 0; k < K_REP; ++k) {
            seg_start[(size_t)k * n + d] = run;
            run += cnt_k[k];
        }
        if (d == n - 1) row_start[n] = run;
        dinv[d] = rsqrtf(1.0f + wsum * (1.0f / 16777216.0f));   // self-loop weight 1
    }
}

// Scatter each edge into its precomputed (replica,dst,rank) CSR slot. ZERO atomics.
__global__ __launch_bounds__(256) void build_csr_kernel(const int* __restrict__ src,
                                                        const int* __restrict__ dst,
                                                        const float* __restrict__ w,
                                                        const float* __restrict__ dinv,
                                                        const int* __restrict__ seg_start,
                                                        const int* __restrict__ rank,
                                                        int2* __restrict__ csr,
                                                        int n, int e) {
    int i = blockIdx.x * 256 + threadIdx.x;   // MUST match hist's edge->replica mapping
    if (i >= e) return;
    int s = src[i], d = dst[i];
    float norm = dinv[s] * w[i] * dinv[d];
    int k = blockIdx.x & (K_REP - 1);
    int pos = seg_start[(size_t)k * n + d] + rank[i];
    csr[pos] = make_int2(s, __float_as_int(norm));
}

// Pack W into MFMA B-fragment layout, split bf16 hi/lo. Column-pair permutation:
// tile t (t=2p+q) covers actual cols 32p + 2j + q (j = lane&15), so the GEMM
// epilogue can pack tiles 2p,2p+1 into one dword of adjacent columns.
// Index: (t*4 + s)*64 + lane; element j of lane's frag = W[32s + (lane>>4)*8 + j][col].
__global__ __launch_bounds__(256) void packW_kernel(const float* __restrict__ W,
                                                    uint4* __restrict__ wphi,
                                                    uint4* __restrict__ wplo) {
    int idx = blockIdx.x * 256 + threadIdx.x;
    if (idx >= 8 * 4 * 64) return;
    int l = idx & 63;
    int s = (idx >> 6) & 3;
    int t = idx >> 8;
    int p = t >> 1, q = t & 1;
    int col = 32 * p + 2 * (l & 15) + q;
    int kbase = 32 * s + (l >> 4) * 8;
    uint hi[8], lo[8];
    #pragma unroll
    for (int j = 0; j < 8; ++j) {
        float w = W[(size_t)(kbase + j) * F + col];
        ushort h = f2bf(w);
        lo[j] = f2bf(w - bf2f(h));
        hi[j] = h;
    }
    uint4 vh, vl;
    vh.x = hi[0] | (hi[1] << 16); vh.y = hi[2] | (hi[3] << 16);
    vh.z = hi[4] | (hi[5] << 16); vh.w = hi[6] | (hi[7] << 16);
    vl.x = lo[0] | (lo[1] << 16); vl.y = lo[2] | (lo[3] << 16);
    vl.z = lo[4] | (lo[5] << 16); vl.w = lo[6] | (lo[7] << 16);
    wphi[idx] = vh;
    wplo[idx] = vl;
}

#define XPAD 136  // 128 + 8 bf16 pad: 272B row stride -> only 2-way bank alias (free)

// h = x @ W via MFMA, split-bf16 (hi+lo) inputs for near-f32 accuracy, bf16 output.
// Block: 64 rows x 128 cols, 4 waves; wave w owns rows 16w..16w+15, all 8 col-tiles.
__global__ __launch_bounds__(256) void gemm_kernel(const float* __restrict__ x,
                                                   const uint4* __restrict__ wphi,
                                                   const uint4* __restrict__ wplo,
                                                   ushort* __restrict__ hb, int n) {
    __shared__ ushort xhi[64][XPAD];
    __shared__ ushort xlo[64][XPAD];
    int row0 = blockIdx.x * 64;
    int t = threadIdx.x;
    // stage: 64x128 f32 -> split bf16 in LDS (each thread: 8 float4 loads)
    #pragma unroll
    for (int i = 0; i < 8; ++i) {
        int v = t + 256 * i;          // 0..2047 float4 slots
        int r = v >> 5, c4 = v & 31;
        int row = row0 + r;
        float4 val = (row < n) ? ((const float4*)x)[(size_t)row * 32 + c4]
                               : make_float4(0.f, 0.f, 0.f, 0.f);
        ushort h0 = f2bf(val.x), h1 = f2bf(val.y), h2 = f2bf(val.z), h3 = f2bf(val.w);
        ushort l0 = f2bf(val.x - bf2f(h0)), l1 = f2bf(val.y - bf2f(h1));
        ushort l2 = f2bf(val.z - bf2f(h2)), l3 = f2bf(val.w - bf2f(h3));
        *(ushort4*)&xhi[r][c4 * 4] = make_ushort4(h0, h1, h2, h3);
        *(ushort4*)&xlo[r][c4 * 4] = make_ushort4(l0, l1, l2, l3);
    }
    __syncthreads();

    int wv = t >> 6, l = t & 63;
    int m = l & 15, quad = l >> 4;
    f32x4 acc[8];
    #pragma unroll
    for (int i = 0; i < 8; ++i) acc[i] = (f32x4){0.f, 0.f, 0.f, 0.f};

    #pragma unroll
    for (int s = 0; s < 4; ++s) {
        bf16x8 ahi = *(const bf16x8*)&xhi[16 * wv + m][32 * s + quad * 8];
        bf16x8 alo = *(const bf16x8*)&xlo[16 * wv + m][32 * s + quad * 8];
        #pragma unroll
        for (int tt = 0; tt < 8; ++tt) {
            int widx = (tt * 4 + s) * 64 + l;
            U4B8 bh, bl;
            bh.u = wphi[widx];
            bl.u = wplo[widx];
            acc[tt] = __builtin_amdgcn_mfma_f32_16x16x32_bf16(ahi, bh.v, acc[tt], 0, 0, 0);
            acc[tt] = __builtin_amdgcn_mfma_f32_16x16x32_bf16(alo, bh.v, acc[tt], 0, 0, 0);
            acc[tt] = __builtin_amdgcn_mfma_f32_16x16x32_bf16(ahi, bl.v, acc[tt], 0, 0, 0);
        }
    }

    // epilogue: C/D layout col=lane&15 (permuted), row=quad*4+reg.
    // tiles 2p (even cols) + 2p+1 (odd cols) pack into one dword at col 32p+2m.
    #pragma unroll
    for (int r = 0; r < 4; ++r) {
        int row = row0 + 16 * wv + quad * 4 + r;
        if (row < n) {
            uint* outp = (uint*)hb + (size_t)row * 64;
            #pragma unroll
            for (int p = 0; p < 4; ++p) {
                uint vp = (uint)f2bf(acc[2 * p][r]) | ((uint)f2bf(acc[2 * p + 1][r]) << 16);
                outp[p * 16 + m] = vp;   // coalesced per quad (64B)
            }
        }
    }
}

// One wave per node, 2 bf16 features per lane (one dword). readlane edge broadcast,
// 8-deep explicit gather batch for memory-level parallelism.
__global__ __launch_bounds__(256) void aggregate_kernel(
        const ushort* __restrict__ hb, const int* __restrict__ row_start,
        const int2* __restrict__ csr, const float* __restrict__ dinv,
        const float* __restrict__ b,
        float* __restrict__ out_emb, float* __restrict__ out_relu, int n) {
    int wave = threadIdx.x >> 6;
    int lane = threadIdx.x & 63;
    int i = blockIdx.x * 4 + wave;
    if (i >= n) return;
    int lo = row_start[i], hi = row_start[i + 1];
    float di = dinv[i];
    const uint* h32 = (const uint*)hb;   // one dword = features {2*lane, 2*lane+1}
    uint hvu = h32[(size_t)i * 64 + lane];
    float2 bv = ((const float2*)b)[lane];
    float2 acc;
    acc.x = fmaf(__uint_as_float(hvu << 16) * di, di, bv.x);          // self-loop
    acc.y = fmaf(__uint_as_float(hvu & 0xFFFF0000u) * di, di, bv.y);
    for (int c = lo; c < hi; c += 64) {
        int m = min(64, hi - c);
        int sv = 0, nvi = 0;   // lanes >= m keep (src=0, norm=0) -> harmless padding
        if (lane < m) { int2 en = csr[c + lane]; sv = en.x; nvi = en.y; }
        int mp = (m + 7) & ~7;
        for (int j = 0; j < mp; j += 8) {
            int ss[8]; float nw[8]; uint g[8];
            #pragma unroll
            for (int u = 0; u < 8; ++u) {
                ss[u] = __builtin_amdgcn_readlane(sv, j + u);
                nw[u] = __uint_as_float((uint)__builtin_amdgcn_readlane(nvi, j + u));
            }
            #pragma unroll
            for (int u = 0; u < 8; ++u)
                g[u] = h32[(size_t)ss[u] * 64 + lane];   // 8 independent 256B row gathers
            #pragma unroll
            for (int u = 0; u < 8; ++u) {
                acc.x = fmaf(__uint_as_float(g[u] << 16), nw[u], acc.x);
                acc.y = fmaf(__uint_as_float(g[u] & 0xFFFF0000u), nw[u], acc.y);
            }
        }
    }
    ((float2*)out_emb)[(size_t)i * 64 + lane] = acc;
    ((float2*)out_relu)[(size_t)i * 64 + lane] =
        make_float2(fmaxf(acc.x, 0.f), fmaxf(acc.y, 0.f));
}

extern "C" void kernel_launch(void* const* d_in, const int* in_sizes, int n_in,
                              void* d_out, int out_size, void* d_ws, size_t ws_size,
                              hipStream_t stream) {
    const float* x  = (const float*)d_in[0];
    const float* W  = (const float*)d_in[1];
    const float* b  = (const float*)d_in[2];
    const int*   ei = (const int*)d_in[4];
    const float* ew = (const float*)d_in[5];

    int n = in_sizes[0] / F;
    int e = in_sizes[4] / 2;
    const int* src = ei;
    const int* dst = ei + e;

    float* out_emb  = (float*)d_out;
    float* out_relu = out_emb + (size_t)n * F;

    // workspace layout (~52 MB). packed (K_REP*n u64) aliases csr (e int2):
    // packed is dead after scan3; csr is written only in build_csr (after scan3).
    ushort* hb = (ushort*)d_ws;                                  // n*F bf16 (25.6 MB)
    int2* csr = (int2*)(hb + (size_t)n * F);
    unsigned long long* packed = (unsigned long long*)csr;
    size_t shared_elems = (size_t)e > (size_t)K_REP * n ? (size_t)e : (size_t)K_REP * n;
    int*   seg_start  = (int*)(csr + shared_elems);              // K_REP*n
    int*   row_start  = seg_start + (size_t)K_REP * n;           // n+16 (16B-mult)
    float* dinv       = (float*)(row_start + n + 16);            // n
    int*   partials   = (int*)(dinv + n);                        // 1024
    int*   rank       = partials + 1024;                         // e
    uint4* wphi       = (uint4*)(rank + e);                      // 2048 uint4 (32 KB)
    uint4* wplo       = wphi + 2048;                             // 2048 uint4 (32 KB)

    int nb_e    = (e + 255) / 256;
    int nb_scan = (n + 255) / 256;   // 391 for n=100k (scan2 handles <=1024)

    hipMemsetAsync(packed, 0, (size_t)K_REP * n * sizeof(unsigned long long), stream);
    packW_kernel<<<8, 256, 0, stream>>>(W, wphi, wplo);
    hist_kernel<<<nb_e, 256, 0, stream>>>(dst, ew, packed, rank, n, e);
    scan1_kernel<<<nb_scan, 256, 0, stream>>>(packed, partials, n);
    scan2_kernel<<<1, 1024, 0, stream>>>(partials, nb_scan);
    scan3_kernel<<<nb_scan, 256, 0, stream>>>(packed, partials, seg_start,
                                              row_start, dinv, n);
    gemm_kernel<<<(n + 63) / 64, 256, 0, stream>>>(x, wphi, wplo, hb, n);
    build_csr_kernel<<<nb_e, 256, 0, stream>>>(src, dst, ew, dinv, seg_start, rank,
                                               csr, n, e);
    aggregate_kernel<<<(n + 3) / 4, 256, 0, stream>>>(hb, row_start, csr, dinv, b,
                                                      out_emb, out_relu, n);
}